// Round 1
// baseline (57.230 us; speedup 1.0000x reference)
//
#include <hip/hip_runtime.h>

// QuantumLayer: n=8 qubits, RY(x) layer + RY(w) layer + CNOT chain (0->1 ... 6->7),
// measure <Z> on qubit 0 (most significant bit).
//
// Analytic collapse:
//   - product state after both RY layers: qubit q amplitude [cos(th/2), sin(th/2)],
//     th = x[b,q] + w[q]  (RY angles compose on the same qubit)
//   - CNOT chain never targets qubit 0 => P(bit0) invariant
//   - out[b] = cos^2(th0/2) - sin^2(th0/2) = cos(x[b,0] + w[0])

#define BATCH 262144
#define N_QUBITS 8

__global__ __launch_bounds__(256) void qlayer_cos_kernel(
    const float* __restrict__ x,      // [B, 8]
    const float* __restrict__ w,      // [8]
    float* __restrict__ out,          // [B]
    int B)
{
    const float w0 = w[0];            // uniform: scalar-loaded + broadcast
    int b = blockIdx.x * blockDim.x + threadIdx.x;
    if (b < B) {
        float x0 = x[(size_t)b * N_QUBITS];   // column 0, stride-8 read
        out[b] = cosf(x0 + w0);
    }
}

extern "C" void kernel_launch(void* const* d_in, const int* in_sizes, int n_in,
                              void* d_out, int out_size, void* d_ws, size_t ws_size,
                              hipStream_t stream) {
    const float* x = (const float*)d_in[0];   // [262144, 8] fp32
    const float* w = (const float*)d_in[1];   // [8] fp32
    float* out = (float*)d_out;               // [262144] fp32

    const int B = out_size;                   // 262144
    const int block = 256;
    const int grid = (B + block - 1) / block; // 1024 blocks

    qlayer_cos_kernel<<<grid, block, 0, stream>>>(x, w, out, B);
}